// Round 11
// baseline (958.021 us; speedup 1.0000x reference)
//
#include <hip/hip_runtime.h>
#include <math.h>

typedef unsigned char u8;
typedef unsigned short u16;
typedef unsigned int u32;
typedef unsigned long long u64;
typedef __attribute__((ext_vector_type(8))) int int8v;
typedef __attribute__((ext_vector_type(4))) int int4v;
typedef __attribute__((ext_vector_type(4))) float f32x4;

#define B_IMG 16
#define EMB 1536
#define NPATCH 784
#define Q_TOT (B_IMG * NPATCH)   // 12544
#define NCORE 16384
#define BK 128                   // K per staging iter (fp8 bytes) = one MFMA K
#define IMG 224
#define KS 33
#define HALF 16
#define REFINE_W 12.0f

// GEMM tiling: 256x256 tile, 8 waves (2x4), per-wave 128x64, double-buffered LDS
// FROZEN at the R2-verified configuration (527us, MfmaUtil 25.6%, no spill).
// Closed axes (each ~5 GB scratch/thrash + 3-8x regression): phase-split asm
// (R3), counted vmcnt (R5), 32x32 MFMA shape (R4), 128^2 tile (R6), 16-wave
// decomposition (R9: VGPR cap 64 -> 12.5 GB spill). Do not touch k_gemm.
#define BM 256
#define BN 256
#define MBLK (Q_TOT / BM)        // 49
#define NBLK2 (NCORE / BN)       // 64
#define NHALF 256                // 64-col half-blocks per row in cand
#define NKS (EMB / BK)           // 12 K-steps

// ---------- helpers ----------

// monotonic total-order mapping for f32
__device__ __forceinline__ u32 fkey(float f) {
    u32 u = __float_as_uint(f);
    return (u & 0x80000000u) ? ~u : (u | 0x80000000u);
}
__device__ __forceinline__ float fkey_inv(u32 k) {
    u32 u = (k & 0x80000000u) ? (k ^ 0x80000000u) : ~k;
    return __uint_as_float(u);
}

// f32 -> OCP e4m3fn, RNE (saturating)
__device__ __forceinline__ u32 f2e4m3(float f) {
    u32 x = __float_as_uint(f);
    u32 sign = (x >> 24) & 0x80u;
    x &= 0x7fffffffu;
    if (x >= 0x43E00000u) return sign | 0x7Eu;      // >= 448 -> 448
    u32 e = x >> 23;
    if (e >= 121) {                                  // normal e4m3 (>= 2^-6)
        u32 m = x & 0x7fffffu;
        u32 keep = m >> 20;
        u32 rest = m & 0xFFFFFu;
        u32 rnd = (rest > 0x80000u) || (rest == 0x80000u && (keep & 1u));
        u32 mant = keep + rnd;
        u32 e4 = e - 120;
        if (mant == 8) { mant = 0; e4 += 1; }
        return sign | (e4 << 3) | mant;
    }
    float a = __uint_as_float(x);
    u32 q = (u32)(a * 512.0f + 0.5f);                // denormal units of 2^-9
    if (q > 7) return sign | 0x08u;
    return sign | q;
}

// async global->LDS, 16B per lane
__device__ __forceinline__ void async_copy16(const void* gsrc, void* ldst) {
    auto g = reinterpret_cast<const __attribute__((address_space(1))) u32*>(
        reinterpret_cast<uintptr_t>(gsrc));
    auto l = reinterpret_cast<__attribute__((address_space(3))) u32*>(
        reinterpret_cast<uintptr_t>(ldst));
    __builtin_amdgcn_global_load_lds(g, l, 16, 0, 0);
}

// ---------- 1: coreset -> fp8 + row norms (float4 loads, packed u32 stores) ----
__global__ void k_split_cs(const float* __restrict__ cs, u8* __restrict__ cs8,
                           float* __restrict__ b2) {
    __shared__ float sm[4];
    const int n = blockIdx.x;
    const int t = threadIdx.x;
    const float4* src = (const float4*)(cs + (size_t)n * EMB);   // 384 float4
    u32* dst = (u32*)(cs8 + (size_t)n * EMB);                    // 384 u32
    float s = 0.f;
    {
        float4 v = src[t];
        dst[t] = f2e4m3(v.x) | (f2e4m3(v.y) << 8) |
                 (f2e4m3(v.z) << 16) | (f2e4m3(v.w) << 24);
        s += v.x * v.x + v.y * v.y + v.z * v.z + v.w * v.w;
    }
    if (t < 128) {
        float4 v = src[256 + t];
        dst[256 + t] = f2e4m3(v.x) | (f2e4m3(v.y) << 8) |
                       (f2e4m3(v.z) << 16) | (f2e4m3(v.w) << 24);
        s += v.x * v.x + v.y * v.y + v.z * v.z + v.w * v.w;
    }
#pragma unroll
    for (int off = 32; off > 0; off >>= 1) s += __shfl_down(s, off, 64);
    if ((t & 63) == 0) sm[t >> 6] = s;
    __syncthreads();
    if (t == 0) b2[n] = sm[0] + sm[1] + sm[2] + sm[3];
}

// ---------- 2: avgpool(3,1,1) + 2x nearest upsample of layer3,
//              transpose to [q][e], write fp8 (packed u32) + fp32 (float4) ----
__global__ void k_build_x(const float* __restrict__ f2, const float* __restrict__ f3,
                          u8* __restrict__ x8, float* __restrict__ xf) {
    __shared__ float tile[32][33];
    const int tx = threadIdx.x, ty = threadIdx.y;
    const int hw0 = blockIdx.x * 32;
    const int e0 = blockIdx.y * 32;
    const int b = blockIdx.z;
    const int hw = hw0 + tx;
    const bool ok = hw < NPATCH;
    const int h = hw / 28, w = hw - h * 28;
#pragma unroll
    for (int j = 0; j < 4; ++j) {
        const int el = ty + 8 * j;
        const int e = e0 + el;
        float v = 0.f;
        if (ok) {
            if (e < 512) {
                const float* p = f2 + (size_t)(b * 512 + e) * 784;
#pragma unroll
                for (int dy = -1; dy <= 1; ++dy) {
                    int yy = h + dy;
                    if (yy < 0 || yy >= 28) continue;
#pragma unroll
                    for (int dx = -1; dx <= 1; ++dx) {
                        int xx = w + dx;
                        if (xx < 0 || xx >= 28) continue;
                        v += p[yy * 28 + xx];
                    }
                }
            } else {
                const int c = e - 512;
                const int y3 = h >> 1, x3 = w >> 1;
                const float* p = f3 + (size_t)(b * 1024 + c) * 196;
#pragma unroll
                for (int dy = -1; dy <= 1; ++dy) {
                    int yy = y3 + dy;
                    if (yy < 0 || yy >= 14) continue;
#pragma unroll
                    for (int dx = -1; dx <= 1; ++dx) {
                        int xx = x3 + dx;
                        if (xx < 0 || xx >= 14) continue;
                        v += p[yy * 14 + xx];
                    }
                }
            }
            v *= (1.0f / 9.0f);
        }
        tile[el][tx] = v;
    }
    __syncthreads();
    // vectorized write phase: thread t -> e-quad c = t&7, patch row hwl = t>>3.
    // Adjacent lanes write consecutive 16B float4 (xf) / 4B u32 (x8) of the
    // SAME row -> 128B / 32B contiguous segments. LDS reads tile[4c+i][hwl]:
    // bank = 4c+i+hwl (mod 32, 33==1 mod 32) -> exactly 2-way = free (m136).
    {
        const int t = ty * 32 + tx;
        const int c = t & 7;            // e-quad 0..7
        const int hwl = t >> 3;         // 0..31
        const int hw2 = hw0 + hwl;
        if (hw2 < NPATCH) {
            const int q = b * NPATCH + hw2;
            const int e4 = 4 * c;
            float v0 = tile[e4 + 0][hwl];
            float v1 = tile[e4 + 1][hwl];
            float v2 = tile[e4 + 2][hwl];
            float v3 = tile[e4 + 3][hwl];
            *(float4*)(xf + (size_t)q * EMB + e0 + e4) = (float4){v0, v1, v2, v3};
            *(u32*)(x8 + (size_t)q * EMB + e0 + e4) =
                f2e4m3(v0) | (f2e4m3(v1) << 8) |
                (f2e4m3(v2) << 16) | (f2e4m3(v3) << 24);
        }
    }
}

// ---------- 3: MX-fp8 distance GEMM (scales=1.0), top-1 per 64-col half-block ----
// 256x256 tile, BK=128 fp8, 8 waves 2x4, each wave 128x64 via 8x4 16x16x128 MFMAs.
// Double-buffered LDS (4x32KB): STAGE(next) issued BEFORE COMPUTE(cur); one
// __syncthreads per K-step (drain lands after the compute). R2-verified 527us.
// LDS 16B-chunk XOR-swizzled by (row&7), applied on the STAGING SOURCE so
// global_load_lds's lane-contiguous LDS destination is preserved.
// XCD slicing: xcd = bid&7 owns an 8-col-block slice (8x384KB = 3MB B-panel,
// resident in that XCD's 4MB L2 for the whole kernel).
// Rank key = b2[n] - 2*dot (a2[m] is row-constant, dropped).
__global__ __launch_bounds__(512, 2) void k_gemm(
    const u8* __restrict__ x8, const u8* __restrict__ cs8,
    const float* __restrict__ b2, u64* __restrict__ cand) {
    __shared__ __align__(16) u8 sA0[BM * BK];
    __shared__ __align__(16) u8 sA1[BM * BK];
    __shared__ __align__(16) u8 sB0[BN * BK];
    __shared__ __align__(16) u8 sB1[BN * BK];

    const int tid = threadIdx.x;
    const int lane = tid & 63;
    const int wid = tid >> 6;        // 0..7
    const int wy = wid >> 2;         // 0..1 -> 128-row half
    const int wx = wid & 3;          // 0..3 -> 64-col quarter
    const int qd = lane >> 4;        // 0..3
    const int lr = lane & 15;
    const int sw = lr & 7;

    // XCD-aware bijective swizzle: 3136 blocks = 8 xcd * 8 bx-per-xcd * 49 by
    const u32 bid = blockIdx.x;
    const u32 xcd = bid & 7;
    const u32 sl = bid >> 3;                 // 0..391
    const int bx = (int)(xcd * 8 + (sl & 7)); // 0..63
    const int by = (int)(sl >> 3);            // 0..48
    const int m0 = by * BM;
    const int n0 = bx * BN;

    // staging: slot s = tid + j*512; r = s>>3, physical chunk p = s&7
    size_t srcA[4], srcB[4];
    int dst[4];
#pragma unroll
    for (int j = 0; j < 4; ++j) {
        const int s = tid + j * 512;
        const int r = s >> 3, p = s & 7;
        const int col = (p ^ (r & 7)) << 4;
        srcA[j] = (size_t)(m0 + r) * EMB + col;
        srcB[j] = (size_t)(n0 + r) * EMB + col;
        dst[j] = s << 4;
    }

    f32x4 acc[8][4];
#pragma unroll
    for (int i = 0; i < 8; ++i)
#pragma unroll
        for (int j = 0; j < 4; ++j) acc[i][j] = (f32x4){0.f, 0.f, 0.f, 0.f};

    // LDS read byte offsets, swizzle-matched. row&7 == lr&7 for all mi/nj
    // (wy*128, mi*16, wx*64, nj*16 are all multiples of 8).
    // chunk1 = chunk0 ^ 1  ->  byte offset ^ 16.
    const int aoff0 = (wy * 128 + lr) * BK + (((qd * 2) ^ sw) << 4);
    const int boff0 = (wx * 64 + lr) * BK + (((qd * 2) ^ sw) << 4);

#define STAGE(SA, SB, KSI) do {                                                \
        const size_t kk_ = (size_t)(KSI) * BK;                                 \
        _Pragma("unroll")                                                      \
        for (int j_ = 0; j_ < 4; ++j_) {                                       \
            async_copy16(x8 + srcA[j_] + kk_, (SA) + dst[j_]);                 \
            async_copy16(cs8 + srcB[j_] + kk_, (SB) + dst[j_]);                \
        }                                                                      \
    } while (0)

#define COMPUTE(SA, SB) do {                                                   \
        int8v a_[8];                                                           \
        _Pragma("unroll")                                                      \
        for (int mi_ = 0; mi_ < 8; ++mi_) {                                    \
            const int o_ = aoff0 + mi_ * (16 * BK);                            \
            *(int4v*)&a_[mi_] = *(const int4v*)((SA) + o_);                    \
            *(((int4v*)&a_[mi_]) + 1) = *(const int4v*)((SA) + (o_ ^ 16));     \
        }                                                                      \
        _Pragma("unroll")                                                      \
        for (int nj_ = 0; nj_ < 4; ++nj_) {                                    \
            const int ob_ = boff0 + nj_ * (16 * BK);                           \
            int8v b_;                                                          \
            *(int4v*)&b_ = *(const int4v*)((SB) + ob_);                        \
            *(((int4v*)&b_) + 1) = *(const int4v*)((SB) + (ob_ ^ 16));         \
            _Pragma("unroll")                                                  \
            for (int mi_ = 0; mi_ < 8; ++mi_)                                  \
                acc[mi_][nj_] = __builtin_amdgcn_mfma_scale_f32_16x16x128_f8f6f4( \
                    a_[mi_], b_, acc[mi_][nj_], 0, 0, 0, 0x7F7F7F7F, 0, 0x7F7F7F7F); \
        }                                                                      \
    } while (0)

    // K pipeline: 12 steps, unrolled by 2 over the two buffers
    STAGE(sA0, sB0, 0);
    __syncthreads();
    for (int ks = 0; ks < NKS; ks += 2) {
        STAGE(sA1, sB1, ks + 1);
        COMPUTE(sA0, sB0);
        __syncthreads();
        if (ks + 2 < NKS) STAGE(sA0, sB0, ks + 2);
        COMPUTE(sA1, sB1);
        __syncthreads();
    }
#undef STAGE
#undef COMPUTE

    // epilogue: key value = b2[n] - 2*dot ; min per (row, 64-col half-block)
    // C/D layout: col = lane&15 (n), row = quad*4 + reg (m)
    float bb[4];
#pragma unroll
    for (int nj = 0; nj < 4; ++nj) bb[nj] = b2[n0 + wx * 64 + nj * 16 + lr];

#pragma unroll
    for (int mi = 0; mi < 8; ++mi) {
#pragma unroll
        for (int r = 0; r < 4; ++r) {
            u64 best = ~0ull;
#pragma unroll
            for (int nj = 0; nj < 4; ++nj) {
                const int n_g = n0 + wx * 64 + nj * 16 + lr;
                float v = bb[nj] - 2.0f * acc[mi][nj][r];
                u64 key = ((u64)fkey(v) << 32) | (u32)n_g;
                best = best < key ? best : key;
            }
#pragma unroll
            for (int s = 1; s < 16; s <<= 1) {
                u64 o = __shfl_xor(best, s, 64);
                best = best < o ? best : o;
            }
            if (lr == 0) {
                const int m_l = wy * 128 + mi * 16 + qd * 4 + r;
                cand[(size_t)(m0 + m_l) * NHALF + (bx * 4 + wx)] = best;
            }
        }
    }
}

// ---------- 4: exact fp32 refine of near-min candidates ----------
// Wave-shuffle reductions; candidate loops parallel across the 4 waves;
// all EMB-length traffic vectorized as float4 (16 B/lane).
__global__ void k_refine(const u64* __restrict__ cand, const float* __restrict__ xf,
                         const float* __restrict__ cs,
                         float* __restrict__ scores, int* __restrict__ locs) {
    __shared__ float sx[EMB];
    __shared__ float wred_f[4];
    __shared__ u64 wred_u[4];
    __shared__ u64 wbest_s[4];
    __shared__ int clist[16];
    __shared__ int ccount;
    __shared__ float s_a2, s_lim;
    const int row = blockIdx.x;
    const int t = threadIdx.x;
    const int lane = t & 63, wv = t >> 6;

    const u64 mykey = cand[(size_t)row * NHALF + t];
    const float4* xrow = (const float4*)(xf + (size_t)row * EMB);   // 384 float4
    float4* sx4 = (float4*)sx;
    float p = 0.f;
    {
        float4 v = xrow[t];
        sx4[t] = v;
        p += v.x * v.x + v.y * v.y + v.z * v.z + v.w * v.w;
    }
    if (t < 128) {
        float4 v = xrow[256 + t];
        sx4[256 + t] = v;
        p += v.x * v.x + v.y * v.y + v.z * v.z + v.w * v.w;
    }
    if (t == 0) ccount = 0;
    // wave-level: sum(p), min(key)
#pragma unroll
    for (int off = 32; off > 0; off >>= 1) p += __shfl_down(p, off, 64);
    u64 kmin = mykey;
#pragma unroll
    for (int s = 1; s < 64; s <<= 1) {
        u64 o = __shfl_xor(kmin, s, 64);
        kmin = o < kmin ? o : kmin;
    }
    if (lane == 0) { wred_f[wv] = p; wred_u[wv] = kmin; }
    __syncthreads();
    if (t == 0) {
        float a2 = wred_f[0] + wred_f[1] + wred_f[2] + wred_f[3];
        u64 km = wred_u[0];
        km = wred_u[1] < km ? wred_u[1] : km;
        km = wred_u[2] < km ? wred_u[2] : km;
        km = wred_u[3] < km ? wred_u[3] : km;
        s_a2 = a2;
        s_lim = a2 + fkey_inv((u32)(km >> 32)) + REFINE_W;
    }
    __syncthreads();
    {
        float d2a = s_a2 + fkey_inv((u32)(mykey >> 32));
        if (d2a <= s_lim) {
            int pos = atomicAdd(&ccount, 1);
            if (pos < 16) clist[pos] = (int)(mykey & 0xffffffffu);
        }
    }
    __syncthreads();
    const int nc = min(ccount, 16);
    u64 wb = ~0ull;   // meaningful at lane 0 of each wave
    for (int i = wv; i < nc; i += 4) {
        const int n = clist[i];
        const float4* c4 = (const float4*)(cs + (size_t)n * EMB);
        float q = 0.f;
#pragma unroll
        for (int k = 0; k < 6; ++k) {
            float4 cv = c4[lane + k * 64];
            float4 sv = sx4[lane + k * 64];
            float dx = sv.x - cv.x, dy = sv.y - cv.y;
            float dz = sv.z - cv.z, dw = sv.w - cv.w;
            q += dx * dx + dy * dy + dz * dz + dw * dw;
        }
#pragma unroll
        for (int off = 32; off > 0; off >>= 1) q += __shfl_down(q, off, 64);
        if (lane == 0) {
            u64 key = ((u64)fkey(q) << 32) | (u32)n;
            wb = wb < key ? wb : key;
        }
    }
    if (lane == 0) wbest_s[wv] = wb;
    __syncthreads();
    if (t == 0) {
        u64 best = wbest_s[0];
        best = wbest_s[1] < best ? wbest_s[1] : best;
        best = wbest_s[2] < best ? wbest_s[2] : best;
        best = wbest_s[3] < best ? wbest_s[3] : best;
        float d2 = fkey_inv((u32)(best >> 32));
        scores[row] = sqrtf(fmaxf(d2, 1e-12f));
        locs[row] = (int)(best & 0xffffffffu);
    }
}

// ---------- 5: per-image argmax patch ----------
__global__ void k_argmax(const float* __restrict__ scores, const int* __restrict__ locs,
                         float* __restrict__ imgscore, int* __restrict__ nnidx,
                         int* __restrict__ qstar) {
    __shared__ u64 red[4];
    const int b = blockIdx.x, t = threadIdx.x;
    const int lane = t & 63, wv = t >> 6;
    u64 best = 0;
    for (int p = t; p < NPATCH; p += 256) {
        u32 u = __float_as_uint(scores[b * NPATCH + p]);   // scores > 0
        u64 key = ((u64)u << 32) | (u32)(0xFFFFFFFFu - (u32)p);  // tie -> smallest p
        best = best > key ? best : key;
    }
#pragma unroll
    for (int s = 1; s < 64; s <<= 1) {
        u64 o = __shfl_xor(best, s, 64);
        best = o > best ? o : best;
    }
    if (lane == 0) red[wv] = best;
    __syncthreads();
    if (t == 0) {
        u64 k = red[0];
        k = red[1] > k ? red[1] : k;
        k = red[2] > k ? red[2] : k;
        k = red[3] > k ? red[3] : k;
        int p = (int)(0xFFFFFFFFu - (u32)(k & 0xFFFFFFFFu));
        imgscore[b] = __uint_as_float((u32)(k >> 32));
        nnidx[b] = locs[b * NPATCH + p];
        qstar[b] = b * NPATCH + p;
    }
}

// ---------- 6: partial dots nn_sample . coreset, 4-way K-split ----------
__global__ void k_d2nn(const float* __restrict__ cs, const int* __restrict__ nnidx,
                       float* __restrict__ dpart) {
    __shared__ float snn[16 * 384];
    const int t = threadIdx.x;
    const int nb = blockIdx.x & 63, ksl = blockIdx.x >> 6;
    const int n = nb * 256 + t;
    const int k0 = ksl * 384;
#pragma unroll
    for (int j = 0; j < 6; ++j) {
        int fid = t + j * 256;           // 0..1535 float4 slots
        int row = fid / 96;
        int c4 = fid - row * 96;
        ((float4*)snn)[row * 96 + c4] =
            ((const float4*)(cs + (size_t)nnidx[row] * EMB + k0))[c4];
    }
    __syncthreads();
    float acc[16];
#pragma unroll
    for (int b = 0; b < 16; ++b) acc[b] = 0.f;
    const float4* csrow = (const float4*)(cs + (size_t)n * EMB + k0);
    for (int k4 = 0; k4 < 96; ++k4) {
        float4 c4 = csrow[k4];
#pragma unroll
        for (int b = 0; b < 16; ++b) {
            float4 nb4 = ((const float4*)snn)[b * 96 + k4];
            acc[b] += c4.x * nb4.x + c4.y * nb4.y + c4.z * nb4.z + c4.w * nb4.w;
        }
    }
#pragma unroll
    for (int b = 0; b < 16; ++b)
        dpart[((size_t)ksl * 16 + b) * NCORE + n] = acc[b];
}

// ---------- 7: top-9 supports, d_sup, softmax weight, anomaly score ----------
// Wave-shuffle selection; d_sup loops wave-parallel and float4-vectorized.
__global__ void k_topk(const float* __restrict__ dpart, const float* __restrict__ b2,
                       const int* __restrict__ nnidx,
                       const float* __restrict__ cs, const float* __restrict__ xf,
                       const int* __restrict__ qstar, const float* __restrict__ imgscore,
                       float* __restrict__ out_scores) {
    __shared__ float sd2[NCORE];     // 64 KB
    __shared__ float sxq[EMB];       // 6 KB
    __shared__ int sel_idx[9];
    __shared__ float dsup[9];
    __shared__ u64 wred[4];
    const int b = blockIdx.x, t = threadIdx.x;
    const int lane = t & 63, wv = t >> 6;
    const float bnn = b2[nnidx[b]];
    const int q = qstar[b];
    for (int n = t; n < NCORE; n += 256) {
        float dot = dpart[(0 * 16 + b) * NCORE + n] + dpart[(1 * 16 + b) * NCORE + n] +
                    dpart[(2 * 16 + b) * NCORE + n] + dpart[(3 * 16 + b) * NCORE + n];
        sd2[n] = bnn + b2[n] - 2.f * dot;
    }
    {
        const float4* xq4 = (const float4*)(xf + (size_t)q * EMB);
        float4* s4 = (float4*)sxq;
        s4[t] = xq4[t];
        if (t < 128) s4[256 + t] = xq4[256 + t];
    }
    __syncthreads();

    for (int j = 0; j < 9; ++j) {
        u64 best = ~0ull;
        for (int n = t; n < NCORE; n += 256) {
            u64 key = ((u64)fkey(sd2[n]) << 32) | (u32)n;
            best = best < key ? best : key;
        }
#pragma unroll
        for (int s = 1; s < 64; s <<= 1) {
            u64 o = __shfl_xor(best, s, 64);
            best = o < best ? o : best;
        }
        if (lane == 0) wred[wv] = best;
        __syncthreads();
        if (t == 0) {
            u64 k0 = wred[0];
            k0 = wred[1] < k0 ? wred[1] : k0;
            k0 = wred[2] < k0 ? wred[2] : k0;
            k0 = wred[3] < k0 ? wred[3] : k0;
            int sel = (int)(k0 & 0xffffffffu);
            sel_idx[j] = sel;
            sd2[sel] = __uint_as_float(0x7F800000u);   // +inf: exclude later rounds
        }
        __syncthreads();
    }

    // exact d_sup, wave-parallel over the 9 supports, float4
    const float4* sq4 = (const float4*)sxq;
    for (int j = wv; j < 9; j += 4) {
        const int s = sel_idx[j];
        const float4* c4 = (const float4*)(cs + (size_t)s * EMB);
        float p = 0.f;
#pragma unroll
        for (int k = 0; k < 6; ++k) {
            float4 cv = c4[lane + k * 64];
            float4 sv = sq4[lane + k * 64];
            float dx = sv.x - cv.x, dy = sv.y - cv.y;
            float dz = sv.z - cv.z, dw = sv.w - cv.w;
            p += dx * dx + dy * dy + dz * dz + dw * dw;
        }
#pragma unroll
        for (int off = 32; off > 0; off >>= 1) p += __shfl_down(p, off, 64);
        if (lane == 0) dsup[j] = sqrtf(fmaxf(p, 1e-12f));
    }
    __syncthreads();

    if (t == 0) {
        float m = dsup[0];
        for (int j = 1; j < 9; ++j) m = fmaxf(m, dsup[j]);
        float se = 0.f, e0 = 0.f;
        for (int j = 0; j < 9; ++j) {
            float e = expf(dsup[j] - m);
            se += e;
            if (j == 0) e0 = e;
        }
        out_scores[b] = (1.0f - e0 / se) * imgscore[b];
    }
}

// ---------- 8: bilinear in x only: scores[b][28][28] -> Sx[b][28][224] ----------
__global__ void k_bilx(const float* __restrict__ scores, float* __restrict__ Sx) {
    int i = blockIdx.x * 256 + threadIdx.x;
    if (i >= B_IMG * 28 * IMG) return;
    int x = i % IMG;
    int br = i / IMG;
    int r = br % 28, b = br / 28;
    float cx = (x + 0.5f) * 0.125f - 0.5f;
    int x0 = (int)floorf(cx);
    float fx = cx - (float)x0;
    int x1 = min(max(x0 + 1, 0), 27);
    x0 = min(max(x0, 0), 27);
    const float* s = scores + b * NPATCH + r * 28;
    Sx[i] = (1.f - fx) * s[x0] + fx * s[x1];
}

// ---------- 9: fused (bilinear-y + vertical Gaussian): 28-tap row combine ----------
__global__ void k_blur_vf(const float* __restrict__ Sx, float* __restrict__ out1) {
    __shared__ float wv[28];
    const int y = blockIdx.x, b = blockIdx.y, t = threadIdx.x;
    if (t < 28) wv[t] = 0.f;
    __syncthreads();
    if (t == 0) {
        float wsum = 0.f;
        for (int j = 0; j < KS; ++j) {
            float d = (float)(j - HALF);
            wsum += expf(-(d * d) / 32.0f);
        }
        for (int j = 0; j < KS; ++j) {
            int yy = y - HALF + j;
            yy = yy < 0 ? -yy : (yy > 223 ? 446 - yy : yy);
            float cy = (yy + 0.5f) * 0.125f - 0.5f;
            int y0 = (int)floorf(cy);
            float fy = cy - (float)y0;
            int y1 = min(max(y0 + 1, 0), 27);
            y0 = min(max(y0, 0), 27);
            float d = (float)(j - HALF);
            float wkj = expf(-(d * d) / 32.0f) / wsum;
            wv[y0] += (1.f - fy) * wkj;
            wv[y1] += fy * wkj;
        }
    }
    __syncthreads();
    if (t < IMG) {
        float acc = 0.f;
#pragma unroll
        for (int r = 0; r < 28; ++r) acc += wv[r] * Sx[(b * 28 + r) * IMG + t];
        out1[((size_t)b * IMG + y) * IMG + t] = acc;
    }
}

// ---------- 10: horizontal Gaussian (33-tap, reflect), LDS row ----------
__global__ void k_blur_h(const float* __restrict__ out1, float* __restrict__ out) {
    __shared__ float row[IMG];
    __shared__ float wk[KS];
    const int y = blockIdx.x, b = blockIdx.y, t = threadIdx.x;
    if (t < IMG) row[t] = out1[((size_t)b * IMG + y) * IMG + t];
    if (t < KS) {
        float d = (float)(t - HALF);
        wk[t] = expf(-(d * d) / 32.0f);
    }
    __syncthreads();
    if (t < IMG) {
        float wsum = 0.f, acc = 0.f;
#pragma unroll
        for (int j = 0; j < KS; ++j) wsum += wk[j];
#pragma unroll
        for (int j = 0; j < KS; ++j) {
            int xx = t - HALF + j;
            xx = xx < 0 ? -xx : (xx > 223 ? 446 - xx : xx);
            acc += wk[j] * row[xx];
        }
        out[((size_t)b * IMG + y) * IMG + t] = acc / wsum;
    }
}

// ---------- launch ----------
extern "C" void kernel_launch(void* const* d_in, const int* in_sizes, int n_in,
                              void* d_out, int out_size, void* d_ws, size_t ws_size,
                              hipStream_t stream) {
    const float* f2 = (const float*)d_in[0];
    const float* f3 = (const float*)d_in[1];
    const float* cs = (const float*)d_in[2];
    float* out = (float*)d_out;

    char* w = (char*)d_ws;
    auto alloc = [&](size_t bytes) {
        char* p = w;
        w += (bytes + 255) & ~(size_t)255;
        return p;
    };
    u8* x8 = (u8*)alloc((size_t)Q_TOT * EMB);
    float* xf = (float*)alloc((size_t)Q_TOT * EMB * 4);
    u8* cs8 = (u8*)alloc((size_t)NCORE * EMB);
    float* b2 = (float*)alloc(NCORE * 4);
    u64* cand = (u64*)alloc((size_t)Q_TOT * NHALF * 8);
    float* scores = (float*)alloc(Q_TOT * 4);
    int* locs = (int*)alloc(Q_TOT * 4);
    float* imgscore = (float*)alloc(B_IMG * 4);
    int* nnidx = (int*)alloc(B_IMG * 4);
    int* qstar = (int*)alloc(B_IMG * 4);
    float* dpart = (float*)alloc((size_t)4 * B_IMG * NCORE * 4);
    float* Sx = (float*)alloc((size_t)B_IMG * 28 * IMG * 4);
    float* map1 = (float*)alloc((size_t)B_IMG * IMG * IMG * 4);

    k_split_cs<<<NCORE, 256, 0, stream>>>(cs, cs8, b2);
    k_build_x<<<dim3(25, 48, 16), dim3(32, 8), 0, stream>>>(f2, f3, x8, xf);
    k_gemm<<<dim3(MBLK * NBLK2), 512, 0, stream>>>(x8, cs8, b2, cand);
    k_refine<<<Q_TOT, 256, 0, stream>>>(cand, xf, cs, scores, locs);
    k_argmax<<<16, 256, 0, stream>>>(scores, locs, imgscore, nnidx, qstar);
    k_d2nn<<<256, 256, 0, stream>>>(cs, nnidx, dpart);
    k_topk<<<16, 256, 0, stream>>>(dpart, b2, nnidx, cs, xf, qstar, imgscore,
                                   out + B_IMG * IMG * IMG);
    k_bilx<<<(B_IMG * 28 * IMG + 255) / 256, 256, 0, stream>>>(scores, Sx);
    k_blur_vf<<<dim3(IMG, B_IMG), 256, 0, stream>>>(Sx, map1);
    k_blur_h<<<dim3(IMG, B_IMG), 256, 0, stream>>>(map1, out);
}